// Round 1
// baseline (379.447 us; speedup 1.0000x reference)
//
#include <hip/hip_runtime.h>
#include <math.h>

#define NT 2
#define BSZ 4
#define NAT 512
#define NATOMS 2048   // BSZ*NAT
#define NNEI 200      // M total neighbors
#define EMB 100       // EMB_LAST
#define FITH 240
#define DDIM 1600     // EMB * M2
#define M2 16

__device__ __forceinline__ float ftanh(float x) {
    float ax = fabsf(x);
    float e = __expf(2.0f * ax);                 // v_exp_f32 based
    float t = 1.0f - __fdividef(2.0f, e + 1.0f); // fast rcp; e=inf -> t=1
    return (x < 0.0f) ? -t : t;
}

__global__ void dp_atom_kernel(
    const int*   __restrict__ itype,    // (NAT)
    const float* __restrict__ imagedr,  // (BSZ,NAT,200,4)
    const float* __restrict__ davg,     // (NT,200,4)
    const float* __restrict__ dstd,     // (NT,200,4)
    const float* __restrict__ eW0,      // (NT,NT,1,25)
    const float* __restrict__ eb0,      // (NT,NT,25)
    const float* __restrict__ eW1,      // (NT,NT,25,50)
    const float* __restrict__ eb1,      // (NT,NT,50)
    const float* __restrict__ eW2,      // (NT,NT,50,100)
    const float* __restrict__ eb2,      // (NT,NT,100)
    const float* __restrict__ fW0,      // (NT,1600,240)
    const float* __restrict__ fb0,      // (NT,240)
    const float* __restrict__ fW1,      // (NT,240,240)
    const float* __restrict__ fb1,      // (NT,240)
    const float* __restrict__ fW2,      // (NT,240,240)
    const float* __restrict__ fb2,      // (NT,240)
    const float* __restrict__ fW3,      // (NT,240,1)
    const float* __restrict__ fb3,      // (NT,1)
    const float* __restrict__ eshift,   // (NT)
    float*       __restrict__ out)      // [4 Etot][2048 Ei]
{
    __shared__ __align__(16) float4 rn4[NNEI];       // 3.2 KB
    __shared__ __align__(16) float  xyz[4 * EMB];    // 1.6 KB
    __shared__ __align__(16) float  h0s[100 * 25];   // 10 KB
    __shared__ __align__(16) float  smem[100 * 52];  // 20.8 KB: h1 (emb) then D/hA/hB/h2/red (fit)

    const int atom = blockIdx.x;      // 0..2047
    const int n    = atom & (NAT - 1);
    const int tid  = threadIdx.x;
    const int t    = itype[n];        // atom type 0/1

    // ---- Phase 0: Rn into LDS ----
    for (int m = tid; m < NNEI; m += 256) {
        float4 dr = ((const float4*)imagedr)[(size_t)atom * NNEI + m];
        float R = dr.x;
        float Rsafe = (R > 1e-5f) ? R : 1.0f;
        float u = (R - 0.5f) * (1.0f / 5.5f);
        float uu = u * u;
        float mid = (u * uu * (-6.0f * uu + 15.0f * u - 10.0f) + 1.0f) / Rsafe;
        float S = 0.0f;
        if (R > 0.0f && R < 0.5f)      S = 1.0f / Rsafe;
        else if (R > 0.5f && R < 6.0f) S = mid;
        float sr = (fabsf(R) > 1e-5f) ? (S / Rsafe) : 0.0f;
        float4 av = ((const float4*)davg)[t * NNEI + m];
        float4 sd = ((const float4*)dstd)[t * NNEI + m];
        float4 rv;
        rv.x = (S          - av.x) / sd.x;
        rv.y = (sr * dr.y  - av.y) / sd.y;
        rv.z = (sr * dr.z  - av.z) / sd.z;
        rv.w = (sr * dr.w  - av.w) / sd.w;
        rn4[m] = rv;
    }
    for (int i = tid; i < 4 * EMB; i += 256) xyz[i] = 0.0f;

    // ---- Embedding: per-channel threads ----
    const int c  = tid & 127;  // channel (active < 100)
    const int mh = tid >> 7;   // m half: 0 -> m 0..49, 1 -> m 50..99
    float xp0 = 0.0f, xp1 = 0.0f, xp2 = 0.0f, xp3 = 0.0f;

    for (int j = 0; j < NT; ++j) {
        const int wb = t * NT + j;
        const float* W0 = eW0 + wb * 25;
        const float* B0 = eb0 + wb * 25;
        const float* W1 = eW1 + wb * 25 * 50;
        const float* B1 = eb1 + wb * 50;
        const float* W2 = eW2 + wb * 50 * 100;
        const float* B2 = eb2 + wb * 100;

        __syncthreads();  // rn4 ready (j=0) / h0s,h1 reuse safe (j=1)

        // E1: h0s[m*25+a] = tanh(s*W0[a]+b0[a]), m in [0,100)
        for (int idx = tid; idx < 2500; idx += 256) {
            int m = idx / 25, a = idx - m * 25;
            float s = rn4[j * 100 + m].x;
            h0s[idx] = ftanh(fmaf(s, W0[a], B0[a]));
        }
        __syncthreads();

        // E2: h1[m][cc] = tanh(h0 . W1col) + h0[cc%25], rows padded to 52
        for (int idx = tid; idx < 5000; idx += 256) {
            int m = idx / 50, cc = idx - m * 50;
            const float* h0m = h0s + m * 25;
            float acc = B1[cc];
#pragma unroll
            for (int a = 0; a < 25; ++a) acc = fmaf(h0m[a], W1[a * 50 + cc], acc);
            int sk = (cc < 25) ? cc : cc - 25;
            smem[m * 52 + cc] = ftanh(acc) + h0m[sk];
        }
        for (int idx = tid; idx < 200; idx += 256)
            smem[(idx >> 1) * 52 + 50 + (idx & 1)] = 0.0f;  // zero pads
        __syncthreads();

        // E3: G[m][c] = tanh(h1 . W2col_c) + h1[m][c%50]; accumulate xyz partials
        if (c < EMB) {
            float w2c[52];
#pragma unroll
            for (int a = 0; a < 50; ++a) w2c[a] = W2[a * EMB + c];
            w2c[50] = 0.0f; w2c[51] = 0.0f;
            const float bc = B2[c];
            const int sk = (c < 50) ? c : c - 50;
            for (int i = 0; i < 50; ++i) {
                int m = mh * 50 + i;
                const float* h1m = smem + m * 52;
                float acc = bc;
#pragma unroll
                for (int q = 0; q < 13; ++q) {
                    float4 hv = ((const float4*)h1m)[q];
                    acc = fmaf(hv.x, w2c[4 * q + 0], acc);
                    acc = fmaf(hv.y, w2c[4 * q + 1], acc);
                    acc = fmaf(hv.z, w2c[4 * q + 2], acc);
                    acc = fmaf(hv.w, w2c[4 * q + 3], acc);
                }
                float g = ftanh(acc) + h1m[sk];
                float4 rm = rn4[j * 100 + m];
                xp0 = fmaf(rm.x, g, xp0);
                xp1 = fmaf(rm.y, g, xp1);
                xp2 = fmaf(rm.z, g, xp2);
                xp3 = fmaf(rm.w, g, xp3);
            }
        }
    }
    __syncthreads();

    // ---- xyz reduction (scaled by 1/200) ----
    const float inv = 1.0f / 200.0f;
    if (mh == 0 && c < EMB) {
        xyz[0 * EMB + c] = xp0 * inv; xyz[1 * EMB + c] = xp1 * inv;
        xyz[2 * EMB + c] = xp2 * inv; xyz[3 * EMB + c] = xp3 * inv;
    }
    __syncthreads();
    if (mh == 1 && c < EMB) {
        xyz[0 * EMB + c] += xp0 * inv; xyz[1 * EMB + c] += xp1 * inv;
        xyz[2 * EMB + c] += xp2 * inv; xyz[3 * EMB + c] += xp3 * inv;
    }
    __syncthreads();

    // ---- D[c*16+d] = sum_k xyz[k][c]*xyz[k][d] (into smem, h1 dead) ----
    float* Dld = smem;
    for (int idx = tid; idx < DDIM; idx += 256) {
        int cc = idx >> 4, d = idx & 15;
        float acc = xyz[cc] * xyz[d]
                  + xyz[EMB + cc]     * xyz[EMB + d]
                  + xyz[2 * EMB + cc] * xyz[2 * EMB + d]
                  + xyz[3 * EMB + cc] * xyz[3 * EMB + d];
        Dld[idx] = acc;
    }
    __syncthreads();

    float* hA  = smem + DDIM;          // 240
    float* hB  = hA + FITH;            // 240
    float* h2  = hB + FITH;            // 240
    float* red = h2 + FITH;            // 4

    // ---- fit layer 0: 1600 -> 240 ----
    if (tid < FITH) {
        const float* W = fW0 + (size_t)t * DDIM * FITH;
        float acc = fb0[t * FITH + tid];
        for (int f = 0; f < DDIM; f += 4) {
            float4 dv = *(const float4*)(Dld + f);
            acc = fmaf(dv.x, W[(f + 0) * FITH + tid], acc);
            acc = fmaf(dv.y, W[(f + 1) * FITH + tid], acc);
            acc = fmaf(dv.z, W[(f + 2) * FITH + tid], acc);
            acc = fmaf(dv.w, W[(f + 3) * FITH + tid], acc);
        }
        hA[tid] = ftanh(acc);
    }
    __syncthreads();
    // ---- fit layer 1 ----
    if (tid < FITH) {
        const float* W = fW1 + t * FITH * FITH;
        float acc = fb1[t * FITH + tid];
        for (int f = 0; f < FITH; f += 4) {
            float4 hv = *(const float4*)(hA + f);
            acc = fmaf(hv.x, W[(f + 0) * FITH + tid], acc);
            acc = fmaf(hv.y, W[(f + 1) * FITH + tid], acc);
            acc = fmaf(hv.z, W[(f + 2) * FITH + tid], acc);
            acc = fmaf(hv.w, W[(f + 3) * FITH + tid], acc);
        }
        hB[tid] = hA[tid] + ftanh(acc);
    }
    __syncthreads();
    // ---- fit layer 2 ----
    if (tid < FITH) {
        const float* W = fW2 + t * FITH * FITH;
        float acc = fb2[t * FITH + tid];
        for (int f = 0; f < FITH; f += 4) {
            float4 hv = *(const float4*)(hB + f);
            acc = fmaf(hv.x, W[(f + 0) * FITH + tid], acc);
            acc = fmaf(hv.y, W[(f + 1) * FITH + tid], acc);
            acc = fmaf(hv.z, W[(f + 2) * FITH + tid], acc);
            acc = fmaf(hv.w, W[(f + 3) * FITH + tid], acc);
        }
        h2[tid] = hB[tid] + ftanh(acc);
    }
    __syncthreads();
    // ---- final dot + shifts ----
    float p = 0.0f;
    if (tid < FITH) p = h2[tid] * fW3[t * FITH + tid];
#pragma unroll
    for (int off = 32; off > 0; off >>= 1) p += __shfl_down(p, off, 64);
    if ((tid & 63) == 0) red[tid >> 6] = p;
    __syncthreads();
    if (tid == 0) {
        float e = red[0] + red[1] + red[2] + red[3] + fb3[t] + eshift[t];
        out[4 + atom] = e;
    }
}

__global__ void etot_kernel(float* __restrict__ out) {
    const int b = blockIdx.x;  // 0..3
    float s = 0.0f;
    for (int n = threadIdx.x; n < NAT; n += 256) s += out[4 + b * NAT + n];
#pragma unroll
    for (int off = 32; off > 0; off >>= 1) s += __shfl_down(s, off, 64);
    __shared__ float rr[4];
    if ((threadIdx.x & 63) == 0) rr[threadIdx.x >> 6] = s;
    __syncthreads();
    if (threadIdx.x == 0) out[b] = rr[0] + rr[1] + rr[2] + rr[3];
}

extern "C" void kernel_launch(void* const* d_in, const int* in_sizes, int n_in,
                              void* d_out, int out_size, void* d_ws, size_t ws_size,
                              hipStream_t stream) {
    const int*   itype   = (const int*)  d_in[1];
    const float* imagedr = (const float*)d_in[3];
    const float* davg    = (const float*)d_in[5];
    const float* dstd    = (const float*)d_in[6];
    const float* eW0     = (const float*)d_in[7];
    const float* eb0     = (const float*)d_in[8];
    const float* eW1     = (const float*)d_in[9];
    const float* eb1     = (const float*)d_in[10];
    const float* eW2     = (const float*)d_in[11];
    const float* eb2     = (const float*)d_in[12];
    const float* fW0     = (const float*)d_in[13];
    const float* fb0     = (const float*)d_in[14];
    const float* fW1     = (const float*)d_in[15];
    const float* fb1     = (const float*)d_in[16];
    const float* fW2     = (const float*)d_in[17];
    const float* fb2     = (const float*)d_in[18];
    const float* fW3     = (const float*)d_in[19];
    const float* fb3     = (const float*)d_in[20];
    const float* eshift  = (const float*)d_in[21];
    float* out = (float*)d_out;

    dp_atom_kernel<<<NATOMS, 256, 0, stream>>>(
        itype, imagedr, davg, dstd,
        eW0, eb0, eW1, eb1, eW2, eb2,
        fW0, fb0, fW1, fb1, fW2, fb2, fW3, fb3,
        eshift, out);
    etot_kernel<<<BSZ, 256, 0, stream>>>(out);
}